// Round 8
// baseline (39.556 us; speedup 1.0000x reference)
//
#include <hip/hip_runtime.h>
#include <hip/hip_bf16.h>

#define DM 2048
#define BB 64
#define SS 32
#define CC 8
#define KP 16   // k-split across blocks
#define KR 128  // k-range per block (KP*KR = DM)

typedef __attribute__((ext_vector_type(8))) short short8;
typedef __attribute__((ext_vector_type(4))) short short4v;
typedef __attribute__((ext_vector_type(4))) float f32x4;

static __device__ __forceinline__ short f2bf(float f) {
  union { __hip_bfloat16 h; short s; } u;
  u.h = __float2bfloat16(f);  // RNE; compiler fuses to v_cvt_pk_bf16_f32
  return u.s;
}

// K1: u16[b][k] = bf16(sum_c controls[c][b][k]).  grid 256 x 128
__global__ void k1_sum_bf16(const float* __restrict__ controls,
                            short* __restrict__ u16) {
  const int idx = blockIdx.x * 128 + threadIdx.x;  // 32768 = 64b * 512 kq
  const int b = idx >> 9;
  const int k = (idx & 511) * 4;
  float4 s = make_float4(0.f, 0.f, 0.f, 0.f);
#pragma unroll
  for (int c = 0; c < CC; ++c) {
    const float4 v = *reinterpret_cast<const float4*>(
        controls + ((size_t)c * BB + b) * DM + k);
    s.x += v.x; s.y += v.y; s.z += v.z; s.w += v.w;
  }
  short4v o = {f2bf(s.x), f2bf(s.y), f2bf(s.z), f2bf(s.w)};
  *reinterpret_cast<short4v*>(u16 + (size_t)b * DM + k) = o;
}

// MFMA GEMM: part[kp][b][e] = sum_{k in kp} A[b][k] * W[e][k]
// r7 wave shape (64b x 16e x 128k, 4 m-tile accs sharing one W fragment),
// but W is now staged via global_load_lds into a PER-WAVE 8 KB LDS tile:
// 8 outstanding 1KB wave-loads with zero VGPR staging cost -> 64 KB/CU in
// flight (vs ~3 KB with register bursts) -> HBM-bound W stream (r7 was
// latency-bound at ~1.6 TB/s; Little's law needs ~9 KB/CU).
// LDS tile XOR-swizzled at 16B granules (granule g ^ (row&7)) applied on the
// GLOBAL source address (LDS dest must stay linear, m104/m173); same XOR on
// ds_read side -> 2-way bank aliasing (free). No barriers: tiles are
// wave-private. A fragments issued to regs before one vmcnt(0).
// Numerics identical to r7. grid 512 = 32 eblk x 16 kp.
__global__ __launch_bounds__(256, 2) void gemm_mfma(
    const short* __restrict__ abf, const float* __restrict__ w,
    float* __restrict__ part) {
  __shared__ float lw[4][16][128];  // 32 KB; wave wv owns lw[wv]

  const int t    = threadIdx.x;
  const int lane = t & 63;
  const int wv   = t >> 6;
  const int e0   = (blockIdx.x & 31) * 64 + wv * 16;
  const int kp   = blockIdx.x >> 5;
  const int k0   = kp * KR;

  // ---- stage W tile (16 rows x 128 fp32), swizzled source, linear LDS dest.
  // instr i covers rows 2i,2i+1: lane l -> row 2i+(l>>5), granule g=l&31;
  // source granule = g ^ (row&7)  (permutes within each 512B row segment:
  // still fully coalesced).
  {
    const int rl = lane >> 5;
    const int g  = lane & 31;
    float* ldsb = &lw[wv][0][0];
#pragma unroll
    for (int i = 0; i < 8; ++i) {
      const int r = 2 * i + rl;
      const float* src =
          w + (size_t)(e0 + r) * DM + k0 + ((g ^ (r & 7)) << 2);
      __builtin_amdgcn_global_load_lds(
          (const __attribute__((address_space(1))) void*)src,
          (__attribute__((address_space(3))) void*)(ldsb + i * 256), 16, 0, 0);
    }
  }

  // ---- A fragments: 16 x short8 into regs, issued before the single wait.
  const int r  = lane & 15;        // m for A-frags, n(=e) for B-frag
  const int kc = (lane >> 4) * 8;  // k sub-offset within 32
  const short* ap = abf + (size_t)r * DM + k0 + kc;
  short8 a0[4], a1[4], a2[4], a3[4];
#pragma unroll
  for (int s = 0; s < 4; ++s) {
    const int ko = s * 32;
    a0[s] = *reinterpret_cast<const short8*>(ap + ko);
    a1[s] = *reinterpret_cast<const short8*>(ap + (size_t)16 * DM + ko);
    a2[s] = *reinterpret_cast<const short8*>(ap + (size_t)32 * DM + ko);
    a3[s] = *reinterpret_cast<const short8*>(ap + (size_t)48 * DM + ko);
  }

  asm volatile("s_waitcnt vmcnt(0)" ::: "memory");
  __builtin_amdgcn_sched_barrier(0);

  f32x4 acc0 = {0.f, 0.f, 0.f, 0.f}, acc1 = {0.f, 0.f, 0.f, 0.f};
  f32x4 acc2 = {0.f, 0.f, 0.f, 0.f}, acc3 = {0.f, 0.f, 0.f, 0.f};

  const float* lwr = &lw[wv][r][0];
  const int q = r & 7;
#pragma unroll
  for (int s = 0; s < 4; ++s) {
    const int g0 = (lane >> 4) * 2 + s * 8;  // logical 16B granule of kc
    const float4 lo =
        *reinterpret_cast<const float4*>(lwr + ((g0 ^ q) << 2));
    const float4 hi =
        *reinterpret_cast<const float4*>(lwr + (((g0 + 1) ^ q) << 2));
    short8 bfrag;
    bfrag[0] = f2bf(lo.x); bfrag[1] = f2bf(lo.y);
    bfrag[2] = f2bf(lo.z); bfrag[3] = f2bf(lo.w);
    bfrag[4] = f2bf(hi.x); bfrag[5] = f2bf(hi.y);
    bfrag[6] = f2bf(hi.z); bfrag[7] = f2bf(hi.w);
    acc0 = __builtin_amdgcn_mfma_f32_16x16x32_bf16(a0[s], bfrag, acc0, 0, 0, 0);
    acc1 = __builtin_amdgcn_mfma_f32_16x16x32_bf16(a1[s], bfrag, acc1, 0, 0, 0);
    acc2 = __builtin_amdgcn_mfma_f32_16x16x32_bf16(a2[s], bfrag, acc2, 0, 0, 0);
    acc3 = __builtin_amdgcn_mfma_f32_16x16x32_bf16(a3[s], bfrag, acc3, 0, 0, 0);
  }

  // D: lane l reg j -> b = base + (l>>4)*4 + j, e = e0 + (l&15)
  const int brow = (lane >> 4) * 4;
  float* pb = part + ((size_t)kp * BB) * DM + e0 + r;
#pragma unroll
  for (int j = 0; j < 4; ++j) {
    pb[(size_t)(brow + j) * DM]      = acc0[j];
    pb[(size_t)(brow + j + 16) * DM] = acc1[j];
    pb[(size_t)(brow + j + 32) * DM] = acc2[j];
    pb[(size_t)(brow + j + 48) * DM] = acc3[j];
  }
}

// R1: v16[b][e] = bf16(sum_kp part[kp][b][e] + 8*bias[e]).  grid 256 x 128
__global__ void reduce_bias_bf16(const float* __restrict__ part,
                                 const float* __restrict__ bias,
                                 short* __restrict__ v16) {
  const int idx = blockIdx.x * 128 + threadIdx.x;  // 32768
  const int b = idx >> 9;
  const int e = (idx & 511) * 4;
  const float4 bb = *reinterpret_cast<const float4*>(bias + e);
  float4 s = make_float4(8.f * bb.x, 8.f * bb.y, 8.f * bb.z, 8.f * bb.w);
#pragma unroll
  for (int kp = 0; kp < KP; ++kp) {
    const float4 p = *reinterpret_cast<const float4*>(
        part + ((size_t)kp * BB + b) * DM + e);
    s.x += p.x; s.y += p.y; s.z += p.z; s.w += p.w;
  }
  short4v o = {f2bf(s.x), f2bf(s.y), f2bf(s.z), f2bf(s.w)};
  *reinterpret_cast<short4v*>(v16 + (size_t)b * DM + e) = o;
}

// K4 fused: out[b][s][e] = seq[b][s][e] + (sum_kp part[kp][b][e] + 8*bo[e])
// grid 512: b = bid>>3, e-eighth = bid&7 (256 e). block 256:
// thread -> e-quad (t&63), s-group s0 = t>>6, 8 s-iterations.
__global__ void k4_fused(const float* __restrict__ seq,
                         const float* __restrict__ part,
                         const float* __restrict__ bias,
                         float* __restrict__ out) {
  const int b  = blockIdx.x >> 3;
  const int e  = (blockIdx.x & 7) * 256 + (threadIdx.x & 63) * 4;
  const int s0 = (threadIdx.x >> 6) * 8;
  const float4 bb = *reinterpret_cast<const float4*>(bias + e);
  float4 pv = make_float4(8.f * bb.x, 8.f * bb.y, 8.f * bb.z, 8.f * bb.w);
#pragma unroll
  for (int kp = 0; kp < KP; ++kp) {
    const float4 p = *reinterpret_cast<const float4*>(
        part + ((size_t)kp * BB + b) * DM + e);
    pv.x += p.x; pv.y += p.y; pv.z += p.z; pv.w += p.w;
  }
  const size_t base = (size_t)b * SS * DM + e;
#pragma unroll
  for (int i = 0; i < 8; ++i) {
    const size_t off = base + (size_t)(s0 + i) * DM;
    const float4 q = *reinterpret_cast<const float4*>(seq + off);
    *reinterpret_cast<float4*>(out + off) =
        make_float4(q.x + pv.x, q.y + pv.y, q.z + pv.z, q.w + pv.w);
  }
}

extern "C" void kernel_launch(void* const* d_in, const int* in_sizes, int n_in,
                              void* d_out, int out_size, void* d_ws,
                              size_t ws_size, hipStream_t stream) {
  const float* seq      = (const float*)d_in[0];
  const float* controls = (const float*)d_in[1];
  // d_in[2..5] = Wq, bq, Wk, bk — mathematically unused (softmax over size-1 axis == 1)
  const float* Wv = (const float*)d_in[6];
  const float* bv = (const float*)d_in[7];
  const float* Wo = (const float*)d_in[8];
  const float* bo = (const float*)d_in[9];
  float* out = (float*)d_out;

  char* ws = (char*)d_ws;
  short* u16  = (short*)(ws);                    // 256 KB bf16 [64][2048]
  short* v16  = (short*)(ws + (256ull << 10));   // 256 KB bf16 [64][2048]
  float* part = (float*)(ws + (1024ull << 10));  // 8 MB fp32 [16][64][2048]

  k1_sum_bf16<<<256, 128, 0, stream>>>(controls, u16);
  gemm_mfma<<<512, 256, 0, stream>>>(u16, Wv, part);
  reduce_bias_bf16<<<256, 128, 0, stream>>>(part, bv, v16);
  gemm_mfma<<<512, 256, 0, stream>>>(v16, Wo, part);
  k4_fused<<<512, 256, 0, stream>>>(seq, part, bo, out);
}